// Round 1
// baseline (227.970 us; speedup 1.0000x reference)
//
#include <hip/hip_runtime.h>

typedef __attribute__((ext_vector_type(8))) short short8;
typedef __attribute__((ext_vector_type(4))) float f32x4;
typedef __attribute__((ext_vector_type(8))) unsigned short ushort8v;
typedef __attribute__((ext_vector_type(4))) unsigned short ushort4v;

#define NB 2
#define TQ 2048
#define TKK 2048
#define EMB 1024
#define NH 16
#define HD 64

__device__ __forceinline__ unsigned short f2bf(float f){
  union { float f; unsigned u; } v; v.f = f;
  unsigned r = v.u + 0x7FFFu + ((v.u >> 16) & 1u);
  return (unsigned short)(r >> 16);
}

// async global->LDS, 16B per lane; LDS dest is wave-uniform base + lane*16
#define GLOAD_LDS16(g, l) __builtin_amdgcn_global_load_lds( \
    (const __attribute__((address_space(1))) void*)(g), \
    (__attribute__((address_space(3))) void*)(l), 16, 0, 0)

// T2 XOR swizzle for 128-byte LDS rows (involution, 16B-aligned)
#define SWZ(row, inner) ((inner) ^ (((row)&7)<<4))

__device__ __forceinline__ void mfma16(const short8& a, const short8& b, f32x4& c){
  asm volatile("v_mfma_f32_16x16x32_bf16 %0, %1, %2, %0" : "+&v"(c) : "v"(a), "v"(b));
}

// ---------------- elementwise f32 -> bf16 ----------------
__global__ __launch_bounds__(256) void cvt_f32_bf16(const float* __restrict__ in,
    unsigned short* __restrict__ out, int n4){
  int i = blockIdx.x*256 + threadIdx.x;
  if (i >= n4) return;
  float4 v = ((const float4*)in)[i];
  ushort4v o;
  o.x = f2bf(v.x); o.y = f2bf(v.y); o.z = f2bf(v.z); o.w = f2bf(v.w);
  ((ushort4v*)out)[i] = o;
}

// ---------------- W [K,N] f32 -> WT [N,K] bf16 ----------------
__global__ __launch_bounds__(256) void wt_transpose(const float* __restrict__ W,
    unsigned short* __restrict__ WT, int K, int N){
  __shared__ unsigned short tile[64][72];
  int k0 = blockIdx.y*64, n0 = blockIdx.x*64;
  int tid = threadIdx.x;
  #pragma unroll
  for (int it=0; it<4; ++it){
    int c = tid + it*256;
    int r = c>>4, c4 = (c&15)*4;
    float4 v = *(const float4*)(W + (long)(k0+r)*N + n0 + c4);
    tile[r][c4+0]=f2bf(v.x); tile[r][c4+1]=f2bf(v.y);
    tile[r][c4+2]=f2bf(v.z); tile[r][c4+3]=f2bf(v.w);
  }
  __syncthreads();
  #pragma unroll
  for (int it=0; it<2; ++it){
    int c = tid + it*256;
    int n = c>>3, k8 = (c&7)*8;
    ushort8v o;
    #pragma unroll
    for (int j=0;j<8;++j) o[j] = tile[k8+j][n];
    *(ushort8v*)(WT + (long)(n0+n)*K + k0 + k8) = o;
  }
}

// ---------------- V part of KVb -> VT[bh][d][t] ----------------
__global__ __launch_bounds__(256) void v_transpose(const unsigned short* __restrict__ KV,
    unsigned short* __restrict__ VT){
  __shared__ unsigned short tile[64][72];
  int bh = blockIdx.y; int b = bh>>4, h = bh&15;
  int t0 = blockIdx.x*64;
  int tid = threadIdx.x;
  #pragma unroll
  for (int it=0; it<2; ++it){
    int c = tid + it*256;
    int r = c>>3, d8 = (c&7)*8;
    ushort8v v = *(const ushort8v*)(KV + (long)(b*TKK + t0 + r)*(2*EMB) + EMB + h*HD + d8);
    #pragma unroll
    for (int j=0;j<8;++j) tile[r][d8+j] = v[j];
  }
  __syncthreads();
  #pragma unroll
  for (int it=0; it<2; ++it){
    int c = tid + it*256;
    int d = c>>3, t8 = (c&7)*8;
    ushort8v o;
    #pragma unroll
    for (int j=0;j<8;++j) o[j] = tile[t8+j][d];
    *(ushort8v*)(VT + (long)(bh*HD + d)*TKK + t0 + t8) = o;
  }
}

// ---------------- GEMM: C[M,N] = A[M,K] @ BT[N,K]^T  (bf16 in, bf16/f32 out) ----------------
template<int OUT_BF16>
__global__ __launch_bounds__(256,2) void gemm_bt(const unsigned short* __restrict__ A,
    const unsigned short* __restrict__ BT, void* __restrict__ Cout,
    int M, int N, int K){
  __shared__ unsigned short Al[128*64];
  __shared__ unsigned short Bl[128*64];
  const int tid = threadIdx.x;
  const int wave = tid>>6, lane = tid&63;
  const int m0 = blockIdx.y*128, n0 = blockIdx.x*128;
  const int wm = (wave>>1)*64, wn = (wave&1)*64;
  const int g = lane>>4, lr = lane&15;
  const int srow = lane>>3;
  const int sinner = (lane&7)*16;
  f32x4 acc[4][4] = {};

  for (int k0=0; k0<K; k0+=64){
    #pragma unroll
    for (int j=0;j<4;++j){
      int chunk = wave*4 + j;
      int row = chunk*8 + srow;
      int kb = SWZ(row, sinner);
      GLOAD_LDS16(A + (long)(m0+row)*K + k0 + (kb>>1), Al + chunk*512);
      GLOAD_LDS16(BT + (long)(n0+row)*K + k0 + (kb>>1), Bl + chunk*512);
    }
    __syncthreads();
    #pragma unroll
    for (int kk=0;kk<2;++kk){
      short8 af[4], bfr[4];
      const int kbyte = kk*64 + g*16;
      #pragma unroll
      for (int i=0;i<4;++i){
        int ar = wm + i*16 + lr;
        af[i] = *(const short8*)((const char*)Al + ar*128 + SWZ(ar, kbyte));
        int br = wn + i*16 + lr;
        bfr[i] = *(const short8*)((const char*)Bl + br*128 + SWZ(br, kbyte));
      }
      #pragma unroll
      for (int i=0;i<4;++i)
        #pragma unroll
        for (int jn=0;jn<4;++jn)
          mfma16(af[i], bfr[jn], acc[i][jn]);
    }
    __syncthreads();
  }
  #pragma unroll
  for (int i=0;i<4;++i){
    int row = m0 + wm + i*16 + g*4;
    #pragma unroll
    for (int jn=0;jn<4;++jn){
      int col = n0 + wn + jn*16 + lr;
      #pragma unroll
      for (int r=0;r<4;++r){
        if (OUT_BF16)
          ((unsigned short*)Cout)[(long)(row+r)*N + col] = f2bf(acc[i][jn][r]);
        else
          ((float*)Cout)[(long)(row+r)*N + col] = acc[i][jn][r];
      }
    }
  }
}

// ---------------- flash attention with linear rel-pos bias ----------------
__global__ __launch_bounds__(256,2) void attn_kernel(const unsigned short* __restrict__ Qb,
    const unsigned short* __restrict__ KVb, const unsigned short* __restrict__ VT,
    const float* __restrict__ w_rel, unsigned short* __restrict__ Ob){
  __shared__ unsigned short Kl[64*64];      // [t][d] swizzled, 128B rows
  __shared__ unsigned short Vl[64*64];      // [d][t] swizzled, 128B rows
  __shared__ unsigned short Pl[4][32*64];   // per-wave P [q][t], 128B rows
  const int bh = blockIdx.y, b = bh>>4, h = bh&15;
  const int q0 = blockIdx.x*128;
  const int tid = threadIdx.x, wave = tid>>6, lane = tid&63;
  const int g = lane>>4, lr = lane&15;
  const int srow = lane>>3, sinner = (lane&7)*16;
  const float C1 = 0.125f*1.44269504f;        // SCALE * log2(e)
  const float wr2 = w_rel[h]*1.44269504f;     // bias in log2 domain

  short8 qf[2][2];
  #pragma unroll
  for (int m=0;m<2;++m)
    #pragma unroll
    for (int kk=0;kk<2;++kk)
      qf[m][kk] = *(const short8*)(Qb + (long)(b*TQ + q0 + wave*32 + m*16 + lr)*EMB + h*HD + kk*32 + g*8);

  f32x4 oacc[2][4] = {};
  float Mx[2][4], Ls[2][4];
  #pragma unroll
  for (int m=0;m<2;++m)
    #pragma unroll
    for (int r=0;r<4;++r){ Mx[m][r] = -1e30f; Ls[m][r] = 0.f; }

  for (int kt=0; kt<TKK; kt+=64){
    // stage K tile [64 t][64 d] and VT tile [64 d][64 t], swizzled via source
    #pragma unroll
    for (int j=0;j<2;++j){
      int chunk = wave*2 + j;
      int row = chunk*8 + srow;
      int kb = SWZ(row, sinner);
      GLOAD_LDS16(KVb + (long)(b*TKK + kt + row)*(2*EMB) + h*HD + (kb>>1), Kl + chunk*512);
      GLOAD_LDS16(VT + (long)(bh*HD + row)*TKK + kt + (kb>>1), Vl + chunk*512);
    }
    __syncthreads();
    // S = Q K^T
    f32x4 sacc[2][4] = {};
    #pragma unroll
    for (int kk=0;kk<2;++kk){
      short8 kf[4];
      const int kbyte = kk*64 + g*16;
      #pragma unroll
      for (int n=0;n<4;++n){
        int trow = n*16 + lr;
        kf[n] = *(const short8*)((const char*)Kl + trow*128 + SWZ(trow, kbyte));
      }
      #pragma unroll
      for (int m=0;m<2;++m)
        #pragma unroll
        for (int n=0;n<4;++n)
          mfma16(qf[m][kk], kf[n], sacc[m][n]);
    }
    // logits (log2 domain) + online softmax
    float tv[4];
    #pragma unroll
    for (int n=0;n<4;++n) tv[n] = (float)(kt + n*16 + lr)*wr2;
    #pragma unroll
    for (int m=0;m<2;++m){
      #pragma unroll
      for (int r=0;r<4;++r){
        float bq = (float)(q0 + wave*32 + m*16 + 4*g + r)*wr2;
        float sv[4];
        float rowmax = -1e30f;
        #pragma unroll
        for (int n=0;n<4;++n){
          float s = fmaf(sacc[m][n][r], C1, bq - tv[n]);
          sv[n] = s;
          rowmax = fmaxf(rowmax, s);
        }
        #pragma unroll
        for (int dd=1; dd<16; dd<<=1)
          rowmax = fmaxf(rowmax, __shfl_xor(rowmax, dd, 64));
        float Mn = fmaxf(Mx[m][r], rowmax);
        float rf = exp2f(Mx[m][r] - Mn);
        float psum = 0.f;
        #pragma unroll
        for (int n=0;n<4;++n){
          float p = exp2f(sv[n] - Mn);
          sv[n] = p; psum += p;
        }
        #pragma unroll
        for (int dd=1; dd<16; dd<<=1)
          psum += __shfl_xor(psum, dd, 64);
        Mx[m][r] = Mn;
        Ls[m][r] = Ls[m][r]*rf + psum;
        #pragma unroll
        for (int n=0;n<4;++n) oacc[m][n][r] *= rf;
        const int prow = m*16 + 4*g + r;
        #pragma unroll
        for (int n=0;n<4;++n)
          *(unsigned short*)((char*)(&Pl[wave][0]) + prow*128 + SWZ(prow, (n*16+lr)*2)) = f2bf(sv[n]);
      }
    }
    __syncthreads();   // P visible; K reads done
    // O += P @ V
    #pragma unroll
    for (int kk=0;kk<2;++kk){
      short8 pf[2], vf[4];
      const int kbyte = kk*64 + g*16;
      #pragma unroll
      for (int m=0;m<2;++m){
        int prow = m*16 + lr;
        pf[m] = *(const short8*)((const char*)(&Pl[wave][0]) + prow*128 + SWZ(prow, kbyte));
      }
      #pragma unroll
      for (int n=0;n<4;++n){
        int vrow = n*16 + lr;
        vf[n] = *(const short8*)((const char*)Vl + vrow*128 + SWZ(vrow, kbyte));
      }
      #pragma unroll
      for (int m=0;m<2;++m)
        #pragma unroll
        for (int n=0;n<4;++n)
          mfma16(pf[m], vf[n], oacc[m][n]);
    }
    __syncthreads();   // all waves done with Kl/Vl before next stage
  }
  // epilogue: O / L -> bf16
  #pragma unroll
  for (int m=0;m<2;++m){
    #pragma unroll
    for (int r=0;r<4;++r){
      float inv = 1.0f / Ls[m][r];
      int q = q0 + wave*32 + m*16 + 4*g + r;
      #pragma unroll
      for (int n=0;n<4;++n){
        int d = n*16 + lr;
        Ob[(long)(b*TQ + q)*EMB + h*HD + d] = f2bf(oacc[m][n][r]*inv);
      }
    }
  }
}

extern "C" void kernel_launch(void* const* d_in, const int* in_sizes, int n_in,
                              void* d_out, int out_size, void* d_ws, size_t ws_size,
                              hipStream_t stream){
  const float* x_q    = (const float*)d_in[0];
  const float* x_kv   = (const float*)d_in[1];
  const float* w_q    = (const float*)d_in[2];
  const float* w_kv   = (const float*)d_in[3];
  const float* w_proj = (const float*)d_in[4];
  const float* w_rel  = (const float*)d_in[5];
  (void)in_sizes; (void)n_in; (void)out_size; (void)ws_size;
  char* ws = (char*)d_ws;
  const size_t MB = 1024*1024;
  unsigned short* Qb   = (unsigned short*)(ws + 0);       // 8 MB
  unsigned short* KVb  = (unsigned short*)(ws + 8*MB);    // 16 MB
  unsigned short* WpT  = (unsigned short*)(ws + 24*MB);   // 2 MB
  unsigned short* WqT  = (unsigned short*)(ws + 26*MB);   // 2 MB
  unsigned short* WkvT = (unsigned short*)(ws + 28*MB);   // 4 MB
  unsigned short* Aq   = (unsigned short*)(ws + 32*MB);   // 8 MB, dead after Q-gemm
  unsigned short* Akv  = (unsigned short*)(ws + 40*MB);   // 8 MB, dead after KV-gemm
  unsigned short* Ob   = Aq;    // reuse (lifetimes disjoint)
  unsigned short* VTt  = Akv;   // reuse (lifetimes disjoint)
  float* out = (float*)d_out;

  cvt_f32_bf16<<<4096, 256, 0, stream>>>(x_q,  Aq,  (NB*TQ*EMB)/4);
  cvt_f32_bf16<<<4096, 256, 0, stream>>>(x_kv, Akv, (NB*TKK*EMB)/4);
  wt_transpose<<<dim3(16,16), 256, 0, stream>>>(w_q,    WqT,  EMB, EMB);
  wt_transpose<<<dim3(32,16), 256, 0, stream>>>(w_kv,   WkvT, EMB, 2*EMB);
  wt_transpose<<<dim3(16,16), 256, 0, stream>>>(w_proj, WpT,  EMB, EMB);
  gemm_bt<1><<<dim3(8,32),  256, 0, stream>>>(Aq,  WqT,  Qb,  NB*TQ, EMB,   EMB);
  gemm_bt<1><<<dim3(16,32), 256, 0, stream>>>(Akv, WkvT, KVb, NB*TKK, 2*EMB, EMB);
  v_transpose<<<dim3(32,32), 256, 0, stream>>>(KVb, VTt);
  attn_kernel<<<dim3(16,32), 256, 0, stream>>>(Qb, KVb, VTt, w_rel, Ob);
  gemm_bt<0><<<dim3(8,32),  256, 0, stream>>>(Ob, WpT, out, NB*TQ, EMB, EMB);
}

// Round 6
// 219.621 us; speedup vs baseline: 1.0380x; 1.0380x over previous
//
#include <hip/hip_runtime.h>

typedef __attribute__((ext_vector_type(8))) short short8;
typedef __attribute__((ext_vector_type(8))) __bf16 bf16x8;
typedef __attribute__((ext_vector_type(4))) float f32x4;
typedef __attribute__((ext_vector_type(8))) unsigned short ushort8v;
typedef __attribute__((ext_vector_type(4))) unsigned short ushort4v;

#define NB 2
#define TQ 2048
#define TKK 2048
#define EMB 1024
#define NH 16
#define HD 64

__device__ __forceinline__ unsigned short f2bf(float f){
  union { float f; unsigned u; } v; v.f = f;
  unsigned r = v.u + 0x7FFFu + ((v.u >> 16) & 1u);
  return (unsigned short)(r >> 16);
}

// async global->LDS, 16B per lane; LDS dest is wave-uniform base + lane*16
#define GLOAD_LDS16(g, l) __builtin_amdgcn_global_load_lds( \
    (const __attribute__((address_space(1))) void*)(g), \
    (__attribute__((address_space(3))) void*)(l), 16, 0, 0)

// T2 XOR swizzle for 128-byte LDS rows (involution, 16B-aligned)
#define SWZ(row, inner) ((inner) ^ (((row)&7)<<4))

// Intrinsic MFMA: compiler-visible -> correct hazard wait-states between
// MFMA writes and dependent VALU reads (inline-asm MFMA is opaque to the
// hazard recognizer -- suspected cause of rounds 2-5 corruption).
__device__ __forceinline__ void mfma16(const short8& a, const short8& b, f32x4& c){
  c = __builtin_amdgcn_mfma_f32_16x16x32_bf16(
        __builtin_bit_cast(bf16x8, a), __builtin_bit_cast(bf16x8, b), c, 0, 0, 0);
}

// ---------------- elementwise f32 -> bf16 ----------------
__global__ __launch_bounds__(256) void cvt_f32_bf16(const float* __restrict__ in,
    unsigned short* __restrict__ out, int n4){
  int i = blockIdx.x*256 + threadIdx.x;
  if (i >= n4) return;
  float4 v = ((const float4*)in)[i];
  ushort4v o;
  o.x = f2bf(v.x); o.y = f2bf(v.y); o.z = f2bf(v.z); o.w = f2bf(v.w);
  ((ushort4v*)out)[i] = o;
}

// ---------------- W [K,N] f32 -> WT [N,K] bf16 ----------------
__global__ __launch_bounds__(256) void wt_transpose(const float* __restrict__ W,
    unsigned short* __restrict__ WT, int K, int N){
  __shared__ unsigned short tile[64][72];
  int k0 = blockIdx.y*64, n0 = blockIdx.x*64;
  int tid = threadIdx.x;
  #pragma unroll
  for (int it=0; it<4; ++it){
    int c = tid + it*256;
    int r = c>>4, c4 = (c&15)*4;
    float4 v = *(const float4*)(W + (long)(k0+r)*N + n0 + c4);
    tile[r][c4+0]=f2bf(v.x); tile[r][c4+1]=f2bf(v.y);
    tile[r][c4+2]=f2bf(v.z); tile[r][c4+3]=f2bf(v.w);
  }
  __syncthreads();
  #pragma unroll
  for (int it=0; it<2; ++it){
    int c = tid + it*256;
    int n = c>>3, k8 = (c&7)*8;
    ushort8v o;
    #pragma unroll
    for (int j=0;j<8;++j) o[j] = tile[k8+j][n];
    *(ushort8v*)(WT + (long)(n0+n)*K + k0 + k8) = o;
  }
}

// ---------------- V part of KVb -> VT[bh][d][t] ----------------
__global__ __launch_bounds__(256) void v_transpose(const unsigned short* __restrict__ KV,
    unsigned short* __restrict__ VT){
  __shared__ unsigned short tile[64][72];
  int bh = blockIdx.y; int b = bh>>4, h = bh&15;
  int t0 = blockIdx.x*64;
  int tid = threadIdx.x;
  #pragma unroll
  for (int it=0; it<2; ++it){
    int c = tid + it*256;
    int r = c>>3, d8 = (c&7)*8;
    ushort8v v = *(const ushort8v*)(KV + (long)(b*TKK + t0 + r)*(2*EMB) + EMB + h*HD + d8);
    #pragma unroll
    for (int j=0;j<8;++j) tile[r][d8+j] = v[j];
  }
  __syncthreads();
  #pragma unroll
  for (int it=0; it<2; ++it){
    int c = tid + it*256;
    int d = c>>3, t8 = (c&7)*8;
    ushort8v o;
    #pragma unroll
    for (int j=0;j<8;++j) o[j] = tile[t8+j][d];
    *(ushort8v*)(VT + (long)(bh*HD + d)*TKK + t0 + t8) = o;
  }
}

// ---------------- GEMM: C[M,N] = A[M,K] @ BT[N,K]^T  (bf16 in, bf16/f32 out) ----------------
template<int OUT_BF16>
__global__ __launch_bounds__(256,2) void gemm_bt(const unsigned short* __restrict__ A,
    const unsigned short* __restrict__ BT, void* __restrict__ Cout,
    int M, int N, int K){
  __shared__ unsigned short Al[128*64];
  __shared__ unsigned short Bl[128*64];
  const int tid = threadIdx.x;
  const int wave = tid>>6, lane = tid&63;
  const int m0 = blockIdx.y*128, n0 = blockIdx.x*128;
  const int wm = (wave>>1)*64, wn = (wave&1)*64;
  const int g = lane>>4, lr = lane&15;
  const int srow = lane>>3;
  const int sinner = (lane&7)*16;
  f32x4 acc[4][4] = {};

  for (int k0=0; k0<K; k0+=64){
    #pragma unroll
    for (int j=0;j<4;++j){
      int chunk = wave*4 + j;
      int row = chunk*8 + srow;
      int kb = SWZ(row, sinner);
      GLOAD_LDS16(A + (long)(m0+row)*K + k0 + (kb>>1), Al + chunk*512);
      GLOAD_LDS16(BT + (long)(n0+row)*K + k0 + (kb>>1), Bl + chunk*512);
    }
    __syncthreads();
    #pragma unroll
    for (int kk=0;kk<2;++kk){
      short8 af[4], bfr[4];
      const int kbyte = kk*64 + g*16;
      #pragma unroll
      for (int i=0;i<4;++i){
        int ar = wm + i*16 + lr;
        af[i] = *(const short8*)((const char*)Al + ar*128 + SWZ(ar, kbyte));
        int br = wn + i*16 + lr;
        bfr[i] = *(const short8*)((const char*)Bl + br*128 + SWZ(br, kbyte));
      }
      #pragma unroll
      for (int i=0;i<4;++i)
        #pragma unroll
        for (int jn=0;jn<4;++jn)
          mfma16(af[i], bfr[jn], acc[i][jn]);
    }
    __syncthreads();
  }
  #pragma unroll
  for (int i=0;i<4;++i){
    int row = m0 + wm + i*16 + g*4;
    #pragma unroll
    for (int jn=0;jn<4;++jn){
      int col = n0 + wn + jn*16 + lr;
      #pragma unroll
      for (int r=0;r<4;++r){
        if (OUT_BF16)
          ((unsigned short*)Cout)[(long)(row+r)*N + col] = f2bf(acc[i][jn][r]);
        else
          ((float*)Cout)[(long)(row+r)*N + col] = acc[i][jn][r];
      }
    }
  }
}

// ---------------- flash attention with linear rel-pos bias ----------------
// Round-1 logic (psum shuffle-reduce, fresh-max rescale every tile), m-loop
// stripped (16 q-rows/wave), q-tile 64, 1024 blocks. Intrinsic MFMA.
__global__ __launch_bounds__(256,4) void attn_kernel(const unsigned short* __restrict__ Qb,
    const unsigned short* __restrict__ KVb, const unsigned short* __restrict__ VT,
    const float* __restrict__ w_rel, unsigned short* __restrict__ Ob){
  __shared__ unsigned short Kl[64*64];      // [t][d] swizzled, 128B rows
  __shared__ unsigned short Vl[64*64];      // [d][t] swizzled, 128B rows
  __shared__ unsigned short Pl[4][16*64];   // per-wave P [q][t], 128B rows, swizzled
  const int bh = blockIdx.y, b = bh>>4, h = bh&15;
  const int q0 = blockIdx.x*64;
  const int tid = threadIdx.x, wave = tid>>6, lane = tid&63;
  const int g = lane>>4, lr = lane&15;
  const int srow = lane>>3, sinner = (lane&7)*16;
  const float C1 = 0.125f*1.44269504f;        // SCALE * log2(e)
  const float wr2 = w_rel[h]*1.44269504f;     // bias in log2 domain
  char* Pw = (char*)(&Pl[wave][0]);

  // Q fragment (A-operand: row = q = lr, k = kk*32 + g*8)
  short8 qf[2];
  #pragma unroll
  for (int kk=0;kk<2;++kk)
    qf[kk] = *(const short8*)(Qb + (long)(b*TQ + q0 + wave*16 + lr)*EMB + h*HD + kk*32 + g*8);

  f32x4 oacc[4] = {};
  float Mx[4], Ls[4];
  #pragma unroll
  for (int r=0;r<4;++r){ Mx[r] = -1e30f; Ls[r] = 0.f; }

  for (int kt=0; kt<TKK; kt+=64){
    // stage K tile [64 t][64 d] and VT tile [64 d][64 t], swizzled via source
    #pragma unroll
    for (int j=0;j<2;++j){
      int chunk = wave*2 + j;
      int row = chunk*8 + srow;
      int kb = SWZ(row, sinner);
      GLOAD_LDS16(KVb + (long)(b*TKK + kt + row)*(2*EMB) + h*HD + (kb>>1), Kl + chunk*512);
      GLOAD_LDS16(VT + (long)(bh*HD + row)*TKK + kt + (kb>>1), Vl + chunk*512);
    }
    __syncthreads();

    // S = Q K^T : sacc[n][r] = S[q-local = 4g+r][t-local = n*16+lr]
    f32x4 sacc[4] = {};
    #pragma unroll
    for (int kk=0;kk<2;++kk){
      short8 kf[4];
      const int kbyte = kk*64 + g*16;
      #pragma unroll
      for (int n=0;n<4;++n){
        int trow = n*16 + lr;
        kf[n] = *(const short8*)((const char*)Kl + trow*128 + SWZ(trow, kbyte));
      }
      #pragma unroll
      for (int n=0;n<4;++n)
        mfma16(qf[kk], kf[n], sacc[n]);
    }

    // logits (log2 domain) + online softmax
    float tv[4];
    #pragma unroll
    for (int n=0;n<4;++n) tv[n] = (float)(kt + n*16 + lr)*wr2;
    #pragma unroll
    for (int r=0;r<4;++r){
      float bq = (float)(q0 + wave*16 + 4*g + r)*wr2;
      float sv[4];
      float rowmax = -1e30f;
      #pragma unroll
      for (int n=0;n<4;++n){
        float s = fmaf(sacc[n][r], C1, bq - tv[n]);
        sv[n] = s;
        rowmax = fmaxf(rowmax, s);
      }
      #pragma unroll
      for (int dd=1; dd<16; dd<<=1)
        rowmax = fmaxf(rowmax, __shfl_xor(rowmax, dd, 64));
      float Mn = fmaxf(Mx[r], rowmax);
      float rf = exp2f(Mx[r] - Mn);
      float psum = 0.f;
      #pragma unroll
      for (int n=0;n<4;++n){
        float p = exp2f(sv[n] - Mn);
        sv[n] = p; psum += p;
      }
      #pragma unroll
      for (int dd=1; dd<16; dd<<=1)
        psum += __shfl_xor(psum, dd, 64);
      Mx[r] = Mn;
      Ls[r] = Ls[r]*rf + psum;
      #pragma unroll
      for (int n=0;n<4;++n) oacc[n][r] *= rf;
      const int prow = 4*g + r;
      #pragma unroll
      for (int n=0;n<4;++n)
        *(unsigned short*)(Pw + prow*128 + SWZ(prow, (n*16+lr)*2)) = f2bf(sv[n]);
    }

    __syncthreads();   // P visible; K reads done

    // O += P @ V  (oacc rows q=4g+r, col=lr)
    #pragma unroll
    for (int kk=0;kk<2;++kk){
      const int kbyte = kk*64 + g*16;
      short8 pf = *(const short8*)(Pw + lr*128 + SWZ(lr, kbyte));
      #pragma unroll
      for (int n=0;n<4;++n){
        int vrow = n*16 + lr;
        short8 vf = *(const short8*)((const char*)Vl + vrow*128 + SWZ(vrow, kbyte));
        mfma16(pf, vf, oacc[n]);
      }
    }

    __syncthreads();   // all waves done with Kl/Vl/Pl before next stage
  }

  // epilogue: O / L -> bf16  (row q = 4g+r, col d = n*16+lr)
  #pragma unroll
  for (int r=0;r<4;++r){
    float inv = 1.0f / Ls[r];
    int q = q0 + wave*16 + 4*g + r;
    #pragma unroll
    for (int n=0;n<4;++n){
      int d = n*16 + lr;
      Ob[(long)(b*TQ + q)*EMB + h*HD + d] = f2bf(oacc[n][r]*inv);
    }
  }
}

extern "C" void kernel_launch(void* const* d_in, const int* in_sizes, int n_in,
                              void* d_out, int out_size, void* d_ws, size_t ws_size,
                              hipStream_t stream){
  const float* x_q    = (const float*)d_in[0];
  const float* x_kv   = (const float*)d_in[1];
  const float* w_q    = (const float*)d_in[2];
  const float* w_kv   = (const float*)d_in[3];
  const float* w_proj = (const float*)d_in[4];
  const float* w_rel  = (const float*)d_in[5];
  (void)in_sizes; (void)n_in; (void)out_size; (void)ws_size;
  char* ws = (char*)d_ws;
  const size_t MB = 1024*1024;
  unsigned short* Qb   = (unsigned short*)(ws + 0);       // 8 MB
  unsigned short* KVb  = (unsigned short*)(ws + 8*MB);    // 16 MB
  unsigned short* WpT  = (unsigned short*)(ws + 24*MB);   // 2 MB
  unsigned short* WqT  = (unsigned short*)(ws + 26*MB);   // 2 MB
  unsigned short* WkvT = (unsigned short*)(ws + 28*MB);   // 4 MB
  unsigned short* Aq   = (unsigned short*)(ws + 32*MB);   // 8 MB, dead after Q-gemm
  unsigned short* Akv  = (unsigned short*)(ws + 40*MB);   // 8 MB, dead after KV-gemm
  unsigned short* Ob   = Aq;    // reuse (lifetimes disjoint)
  unsigned short* VTt  = Akv;   // reuse (lifetimes disjoint)
  float* out = (float*)d_out;

  cvt_f32_bf16<<<4096, 256, 0, stream>>>(x_q,  Aq,  (NB*TQ*EMB)/4);
  cvt_f32_bf16<<<4096, 256, 0, stream>>>(x_kv, Akv, (NB*TKK*EMB)/4);
  wt_transpose<<<dim3(16,16), 256, 0, stream>>>(w_q,    WqT,  EMB, EMB);
  wt_transpose<<<dim3(32,16), 256, 0, stream>>>(w_kv,   WkvT, EMB, 2*EMB);
  wt_transpose<<<dim3(16,16), 256, 0, stream>>>(w_proj, WpT,  EMB, EMB);
  gemm_bt<1><<<dim3(8,32),  256, 0, stream>>>(Aq,  WqT,  Qb,  NB*TQ, EMB,   EMB);
  gemm_bt<1><<<dim3(16,32), 256, 0, stream>>>(Akv, WkvT, KVb, NB*TKK, 2*EMB, EMB);
  v_transpose<<<dim3(32,32), 256, 0, stream>>>(KVb, VTt);
  attn_kernel<<<dim3(32,32), 256, 0, stream>>>(Qb, KVb, VTt, w_rel, Ob);
  gemm_bt<0><<<dim3(8,32),  256, 0, stream>>>(Ob, WpT, out, NB*TQ, EMB, EMB);
}

// Round 7
// 175.613 us; speedup vs baseline: 1.2981x; 1.2506x over previous
//
#include <hip/hip_runtime.h>

typedef __attribute__((ext_vector_type(8))) short short8;
typedef __attribute__((ext_vector_type(8))) __bf16 bf16x8;
typedef __attribute__((ext_vector_type(4))) float f32x4;
typedef __attribute__((ext_vector_type(8))) unsigned short ushort8v;
typedef __attribute__((ext_vector_type(4))) unsigned short ushort4v;

#define NB 2
#define TQ 2048
#define TKK 2048
#define EMB 1024
#define NH 16
#define HD 64

__device__ __forceinline__ unsigned short f2bf(float f){
  union { float f; unsigned u; } v; v.f = f;
  unsigned r = v.u + 0x7FFFu + ((v.u >> 16) & 1u);
  return (unsigned short)(r >> 16);
}
// cheap round-half-up for P (values in [0,256], positive, no NaN)
__device__ __forceinline__ unsigned short f2bfr(float f){
  union { float f; unsigned u; } v; v.f = f;
  return (unsigned short)((v.u + 0x8000u) >> 16);
}

// async global->LDS, 16B per lane; LDS dest is wave-uniform base + lane*16
#define GLOAD_LDS16(g, l) __builtin_amdgcn_global_load_lds( \
    (const __attribute__((address_space(1))) void*)(g), \
    (__attribute__((address_space(3))) void*)(l), 16, 0, 0)

// T2 XOR swizzle for 128-byte LDS rows (involution, 16B-aligned)
#define SWZ(row, inner) ((inner) ^ (((row)&7)<<4))

// Intrinsic MFMA (compiler-visible: hazard wait-states handled; the inline-asm
// version silently corrupted accumulators -- rounds 2-5 post-mortem).
__device__ __forceinline__ void mfma16(const short8& a, const short8& b, f32x4& c){
  c = __builtin_amdgcn_mfma_f32_16x16x32_bf16(
        __builtin_bit_cast(bf16x8, a), __builtin_bit_cast(bf16x8, b), c, 0, 0, 0);
}

// ---------------- elementwise f32 -> bf16 ----------------
__global__ __launch_bounds__(256) void cvt_f32_bf16(const float* __restrict__ in,
    unsigned short* __restrict__ out, int n4){
  int i = blockIdx.x*256 + threadIdx.x;
  if (i >= n4) return;
  float4 v = ((const float4*)in)[i];
  ushort4v o;
  o.x = f2bf(v.x); o.y = f2bf(v.y); o.z = f2bf(v.z); o.w = f2bf(v.w);
  ((ushort4v*)out)[i] = o;
}

// ---------------- W [K,N] f32 -> WT [N,K] bf16 ----------------
__global__ __launch_bounds__(256) void wt_transpose(const float* __restrict__ W,
    unsigned short* __restrict__ WT, int K, int N){
  __shared__ unsigned short tile[64][72];
  int k0 = blockIdx.y*64, n0 = blockIdx.x*64;
  int tid = threadIdx.x;
  #pragma unroll
  for (int it=0; it<4; ++it){
    int c = tid + it*256;
    int r = c>>4, c4 = (c&15)*4;
    float4 v = *(const float4*)(W + (long)(k0+r)*N + n0 + c4);
    tile[r][c4+0]=f2bf(v.x); tile[r][c4+1]=f2bf(v.y);
    tile[r][c4+2]=f2bf(v.z); tile[r][c4+3]=f2bf(v.w);
  }
  __syncthreads();
  #pragma unroll
  for (int it=0; it<2; ++it){
    int c = tid + it*256;
    int n = c>>3, k8 = (c&7)*8;
    ushort8v o;
    #pragma unroll
    for (int j=0;j<8;++j) o[j] = tile[k8+j][n];
    *(ushort8v*)(WT + (long)(n0+n)*K + k0 + k8) = o;
  }
}

// ---------------- V part of KVb -> VT[bh][d][t] ----------------
__global__ __launch_bounds__(256) void v_transpose(const unsigned short* __restrict__ KV,
    unsigned short* __restrict__ VT){
  __shared__ unsigned short tile[64][72];
  int bh = blockIdx.y; int b = bh>>4, h = bh&15;
  int t0 = blockIdx.x*64;
  int tid = threadIdx.x;
  #pragma unroll
  for (int it=0; it<2; ++it){
    int c = tid + it*256;
    int r = c>>3, d8 = (c&7)*8;
    ushort8v v = *(const ushort8v*)(KV + (long)(b*TKK + t0 + r)*(2*EMB) + EMB + h*HD + d8);
    #pragma unroll
    for (int j=0;j<8;++j) tile[r][d8+j] = v[j];
  }
  __syncthreads();
  #pragma unroll
  for (int it=0; it<2; ++it){
    int c = tid + it*256;
    int d = c>>3, t8 = (c&7)*8;
    ushort8v o;
    #pragma unroll
    for (int j=0;j<8;++j) o[j] = tile[t8+j][d];
    *(ushort8v*)(VT + (long)(bh*HD + d)*TKK + t0 + t8) = o;
  }
}

// ---------------- GEMM: C[M,N] = A[M,K] @ BT[N,K]^T  (bf16 in, bf16/f32 out) ----------------
template<int OUT_BF16>
__global__ __launch_bounds__(256,2) void gemm_bt(const unsigned short* __restrict__ A,
    const unsigned short* __restrict__ BT, void* __restrict__ Cout,
    int M, int N, int K){
  __shared__ unsigned short Al[128*64];
  __shared__ unsigned short Bl[128*64];
  const int tid = threadIdx.x;
  const int wave = tid>>6, lane = tid&63;
  const int m0 = blockIdx.y*128, n0 = blockIdx.x*128;
  const int wm = (wave>>1)*64, wn = (wave&1)*64;
  const int g = lane>>4, lr = lane&15;
  const int srow = lane>>3;
  const int sinner = (lane&7)*16;
  f32x4 acc[4][4] = {};

  for (int k0=0; k0<K; k0+=64){
    #pragma unroll
    for (int j=0;j<4;++j){
      int chunk = wave*4 + j;
      int row = chunk*8 + srow;
      int kb = SWZ(row, sinner);
      GLOAD_LDS16(A + (long)(m0+row)*K + k0 + (kb>>1), Al + chunk*512);
      GLOAD_LDS16(BT + (long)(n0+row)*K + k0 + (kb>>1), Bl + chunk*512);
    }
    __syncthreads();
    #pragma unroll
    for (int kk=0;kk<2;++kk){
      short8 af[4], bfr[4];
      const int kbyte = kk*64 + g*16;
      #pragma unroll
      for (int i=0;i<4;++i){
        int ar = wm + i*16 + lr;
        af[i] = *(const short8*)((const char*)Al + ar*128 + SWZ(ar, kbyte));
        int br = wn + i*16 + lr;
        bfr[i] = *(const short8*)((const char*)Bl + br*128 + SWZ(br, kbyte));
      }
      #pragma unroll
      for (int i=0;i<4;++i)
        #pragma unroll
        for (int jn=0;jn<4;++jn)
          mfma16(af[i], bfr[jn], acc[i][jn]);
    }
    __syncthreads();
  }
  #pragma unroll
  for (int i=0;i<4;++i){
    int row = m0 + wm + i*16 + g*4;
    #pragma unroll
    for (int jn=0;jn<4;++jn){
      int col = n0 + wn + jn*16 + lr;
      #pragma unroll
      for (int r=0;r<4;++r){
        if (OUT_BF16)
          ((unsigned short*)Cout)[(long)(row+r)*N + col] = f2bf(acc[i][jn][r]);
        else
          ((float*)Cout)[(long)(row+r)*N + col] = acc[i][jn][r];
      }
    }
  }
}

// ---------------- flash attention, swapped-QK^T, in-lane softmax ----------------
// 8 waves x 16 q-rows = 128 q per block. KV tile = 64. Intrinsic MFMA.
__global__ __launch_bounds__(512,4) void attn_kernel(const unsigned short* __restrict__ Qb,
    const unsigned short* __restrict__ KVb, const unsigned short* __restrict__ VT,
    const float* __restrict__ w_rel, unsigned short* __restrict__ Ob){
  __shared__ unsigned short Kl[64*64];      // [t][d] swizzled, 128B rows
  __shared__ unsigned short Vl[64*64];      // [d][t] swizzled, 128B rows
  __shared__ unsigned short Pl[8][16*64];   // per-wave P [q][t], 128B rows, swizzled
  const int bh = blockIdx.y, b = bh>>4, h = bh&15;
  const int q0 = blockIdx.x*128;
  const int tid = threadIdx.x, wave = tid>>6, lane = tid&63;
  const int g = lane>>4, lr = lane&15;
  const int srow = lane>>3, sinner = (lane&7)*16;
  const float C1 = 0.125f*1.44269504f;        // SCALE * log2(e)
  const float wr2 = w_rel[h]*1.44269504f;     // bias in log2 domain
  const float w64 = 64.0f*wr2;
  char* Pw = (char*)(&Pl[wave][0]);

  // Q fragment (B-operand: col = q = lr, k = kk*32 + g*8)
  short8 qf[2];
  #pragma unroll
  for (int kk=0;kk<2;++kk)
    qf[kk] = *(const short8*)(Qb + (long)(b*TQ + q0 + wave*16 + lr)*EMB + h*HD + kk*32 + g*8);

  // bias: dl[n][r] = (q - t)*wr2 with q = q0+wave*16+lr, t = kt + n*16+4g+r
  const float bq = (float)(q0 + wave*16 + lr)*wr2;
  float dl[4][4];
  #pragma unroll
  for (int n=0;n<4;++n)
    #pragma unroll
    for (int r=0;r<4;++r)
      dl[n][r] = bq - (float)(n*16 + 4*g + r)*wr2;

  short8 ones;
  #pragma unroll
  for (int j=0;j<8;++j) ones[j] = (short)0x3F80;  // bf16 1.0

  f32x4 oacc[4] = {};
  f32x4 lacc = {};
  float Mx = -1e30f;

  for (int kt=0; kt<TKK; kt+=64){
    // stage K tile [64 t][64 d] and VT tile [64 d][64 t], swizzled via source
    {
      int row = wave*8 + srow;
      int kb = SWZ(row, sinner);
      GLOAD_LDS16(KVb + (long)(b*TKK + kt + row)*(2*EMB) + h*HD + (kb>>1), Kl + wave*512);
      GLOAD_LDS16(VT + (long)(bh*HD + row)*TKK + kt + (kb>>1), Vl + wave*512);
    }
    __syncthreads();

    // S^T = K Q^T : lane (g,lr) gets S[q=lr][t-local = n*16 + 4g + r]
    f32x4 sacc[4] = {};
    #pragma unroll
    for (int kk=0;kk<2;++kk){
      short8 kf[4];
      const int kbyte = kk*64 + g*16;
      #pragma unroll
      for (int n=0;n<4;++n){
        int trow = n*16 + lr;
        kf[n] = *(const short8*)((const char*)Kl + trow*128 + SWZ(trow, kbyte));
      }
      #pragma unroll
      for (int n=0;n<4;++n)
        mfma16(kf[n], qf[kk], sacc[n]);
    }

    // logits in log2 domain (all 16 values belong to q-row = lr)
    #pragma unroll
    for (int n=0;n<4;++n)
      #pragma unroll
      for (int r=0;r<4;++r)
        sacc[n][r] = fmaf(sacc[n][r], C1, dl[n][r]);

    // in-lane max over 16, then cross-g (lanes lr, lr+16, lr+32, lr+48)
    float rowmax;
    {
      float a0 = fmaxf(fmaxf(sacc[0][0],sacc[0][1]), fmaxf(sacc[0][2],sacc[0][3]));
      float a1 = fmaxf(fmaxf(sacc[1][0],sacc[1][1]), fmaxf(sacc[1][2],sacc[1][3]));
      float a2 = fmaxf(fmaxf(sacc[2][0],sacc[2][1]), fmaxf(sacc[2][2],sacc[2][3]));
      float a3 = fmaxf(fmaxf(sacc[3][0],sacc[3][1]), fmaxf(sacc[3][2],sacc[3][3]));
      rowmax = fmaxf(fmaxf(a0,a1), fmaxf(a2,a3));
      rowmax = fmaxf(rowmax, __shfl_xor(rowmax, 16, 64));
      rowmax = fmaxf(rowmax, __shfl_xor(rowmax, 32, 64));
    }

    // defer-max: rescale only when max grew by > 8 (log2 units; P <= 2^8)
    if (__any(rowmax > Mx + 8.0f)){
      float Mn = fmaxf(Mx, rowmax);
      float rf = exp2f(Mx - Mn);
      Mx = Mn;
      float rfo[4];
      #pragma unroll
      for (int r=0;r<4;++r) rfo[r] = __shfl(rf, 4*g + r, 64);  // rf for q-local=4g+r
      #pragma unroll
      for (int n=0;n<4;++n)
        #pragma unroll
        for (int r=0;r<4;++r) oacc[n][r] *= rfo[r];
      #pragma unroll
      for (int r=0;r<4;++r) lacc[r] *= rfo[r];
    }

    // P = exp2(s - Mx) -> bf16, packed 8B stores to per-wave LDS
    #pragma unroll
    for (int n=0;n<4;++n){
      ushort4v w;
      #pragma unroll
      for (int r=0;r<4;++r)
        w[r] = f2bfr(exp2f(sacc[n][r] - Mx));
      int inner = 32*n + 8*g;
      *(ushort4v*)(Pw + lr*128 + SWZ(lr, inner)) = w;
    }

    __syncthreads();   // P visible (full fence; also orders vs Kl/Vl reads)

    // O += P @ V ; L += P @ ones  (rows q=4g+r, cols d=n*16+lr)
    #pragma unroll
    for (int kk=0;kk<2;++kk){
      const int kbyte = kk*64 + g*16;
      short8 pf = *(const short8*)(Pw + lr*128 + SWZ(lr, kbyte));
      #pragma unroll
      for (int n=0;n<4;++n){
        int vrow = n*16 + lr;
        short8 vf = *(const short8*)((const char*)Vl + vrow*128 + SWZ(vrow, kbyte));
        mfma16(pf, vf, oacc[n]);
      }
      mfma16(pf, ones, lacc);
    }

    // bias drift for next tile
    #pragma unroll
    for (int n=0;n<4;++n)
      #pragma unroll
      for (int r=0;r<4;++r)
        dl[n][r] -= w64;

    __syncthreads();   // all waves done with Kl/Vl/Pl before next stage
  }

  // epilogue: O / L -> bf16  (row q = 4g+r, col d = n*16+lr)
  #pragma unroll
  for (int r=0;r<4;++r){
    float inv = 1.0f / lacc[r];
    int q = q0 + wave*16 + 4*g + r;
    #pragma unroll
    for (int n=0;n<4;++n){
      int d = n*16 + lr;
      Ob[(long)(b*TQ + q)*EMB + h*HD + d] = f2bf(oacc[n][r]*inv);
    }
  }
}

extern "C" void kernel_launch(void* const* d_in, const int* in_sizes, int n_in,
                              void* d_out, int out_size, void* d_ws, size_t ws_size,
                              hipStream_t stream){
  const float* x_q    = (const float*)d_in[0];
  const float* x_kv   = (const float*)d_in[1];
  const float* w_q    = (const float*)d_in[2];
  const float* w_kv   = (const float*)d_in[3];
  const float* w_proj = (const float*)d_in[4];
  const float* w_rel  = (const float*)d_in[5];
  (void)in_sizes; (void)n_in; (void)out_size; (void)ws_size;
  char* ws = (char*)d_ws;
  const size_t MB = 1024*1024;
  unsigned short* Qb   = (unsigned short*)(ws + 0);       // 8 MB
  unsigned short* KVb  = (unsigned short*)(ws + 8*MB);    // 16 MB
  unsigned short* WpT  = (unsigned short*)(ws + 24*MB);   // 2 MB
  unsigned short* WqT  = (unsigned short*)(ws + 26*MB);   // 2 MB
  unsigned short* WkvT = (unsigned short*)(ws + 28*MB);   // 4 MB
  unsigned short* Aq   = (unsigned short*)(ws + 32*MB);   // 8 MB, dead after Q-gemm
  unsigned short* Akv  = (unsigned short*)(ws + 40*MB);   // 8 MB, dead after KV-gemm
  unsigned short* Ob   = Aq;    // reuse (lifetimes disjoint)
  unsigned short* VTt  = Akv;   // reuse (lifetimes disjoint)
  float* out = (float*)d_out;

  cvt_f32_bf16<<<4096, 256, 0, stream>>>(x_q,  Aq,  (NB*TQ*EMB)/4);
  cvt_f32_bf16<<<4096, 256, 0, stream>>>(x_kv, Akv, (NB*TKK*EMB)/4);
  wt_transpose<<<dim3(16,16), 256, 0, stream>>>(w_q,    WqT,  EMB, EMB);
  wt_transpose<<<dim3(32,16), 256, 0, stream>>>(w_kv,   WkvT, EMB, 2*EMB);
  wt_transpose<<<dim3(16,16), 256, 0, stream>>>(w_proj, WpT,  EMB, EMB);
  gemm_bt<1><<<dim3(8,32),  256, 0, stream>>>(Aq,  WqT,  Qb,  NB*TQ, EMB,   EMB);
  gemm_bt<1><<<dim3(16,32), 256, 0, stream>>>(Akv, WkvT, KVb, NB*TKK, 2*EMB, EMB);
  v_transpose<<<dim3(32,32), 256, 0, stream>>>(KVb, VTt);
  attn_kernel<<<dim3(16,32), 512, 0, stream>>>(Qb, KVb, VTt, w_rel, Ob);
  gemm_bt<0><<<dim3(8,32),  256, 0, stream>>>(Ob, WpT, out, NB*TQ, EMB, EMB);
}